// Round 13
// baseline (604.756 us; speedup 1.0000x reference)
//
#include <hip/hip_runtime.h>

#define NPT  4096
#define NBLK 256
#define NTHR 1024

constexpr float EPSV   = 1e-4f;
constexpr float LN2F   = 0.69314718055994531f;
constexpr float E2     = EPSV * LN2F;          // eps*ln2
constexpr float INV_E2 = 1.0f / E2;            // 1/(eps*ln2)
constexpr float S_U    = 4.0f / LN2F;          // uniformity scale

// LDS layout (floats), column-PAIR packed for v_pk_*_f32:
//   pAx : float4[2048] [0,8192)      (x0,x1,y0,y1) of x-point pairs
//   pBx : float4[2048] [8192,16384)  (z0,z1,G0,G1) of x-point pairs
//   pAy : float4[2048] [16384,24576) (x0,x1,y0,y1) of y-point pairs
//   pBy : float4[2048] [24576,32768) (z0,z1,G0,G1) of y-point pairs
//   part2: float2[1024] [32768,34816) per-row (m,s) partials [lrow][half*8+oct]
#define SMEM_FLOATS 34816
#define SMEM_BYTES  (SMEM_FLOATS * 4)

// ws float offsets
#define WF    0
#define WG    4096
#define WPX0  8192
#define WPX1  12288
#define WPY0  16384
#define WPY1  20480
#define WFFIN 24576
#define WFXV  28672
#define WFYV  32768
#define WULS  36864
#define WCTR  40960     // 512 uints
#define WCNX  41984     // float[4096]: 0.5*||x_i||^2
#define WCNY  46080     // float[4096]: 0.5*||y_j||^2

typedef float v2f __attribute__((ext_vector_type(2)));

__device__ __forceinline__ float fexp2(float x) { return __builtin_amdgcn_exp2f(x); }
__device__ __forceinline__ float flog2(float x) { return __builtin_amdgcn_logf(x); }

__device__ __forceinline__ v2f pk_fma(v2f a, v2f b, v2f c) {
    v2f d;
    asm("v_pk_fma_f32 %0, %1, %2, %3" : "=v"(d) : "v"(a), "v"(b), "v"(c));
    return d;
}
__device__ __forceinline__ v2f pk_add(v2f a, v2f b) {
    v2f d;
    asm("v_pk_add_f32 %0, %1, %2" : "=v"(d) : "v"(a), "v"(b));
    return d;
}
__device__ __forceinline__ float max3f(float a, float b, float c) {
    float d;
    asm("v_max3_f32 %0, %1, %2, %3" : "=v"(d) : "v"(a), "v"(b), "v"(c));
    return d;
}

// VALU-only cross-lane via DPP: 0xB1 xor1, 0x4E xor2,
// 0x141 row_half_mirror (8-lane), 0x140 row_mirror (16-lane).
template<int CTRL>
__device__ __forceinline__ float dppf(float x) {
    return __int_as_float(__builtin_amdgcn_update_dpp(
        __float_as_int(x), __float_as_int(x), CTRL, 0xF, 0xF, false));
}

// system-scope (sc0 sc1) relaxed accessors: bypass non-coherent XCD L2s.
__device__ __forceinline__ float gload(const float* p) {
    return __hip_atomic_load(p, __ATOMIC_RELAXED, __HIP_MEMORY_SCOPE_SYSTEM);
}
__device__ __forceinline__ void gstore(float* p, float v) {
    __hip_atomic_store(p, v, __ATOMIC_RELAXED, __HIP_MEMORY_SCOPE_SYSTEM);
}

// Fence-free GROUP barrier (128 blocks/group). 256x1024, 1 block/CU is the
// proven-safe residency envelope (R8's 2-block/CU deadlocked).
__device__ __forceinline__ void group_barrier(unsigned* base, unsigned target, int b) {
    asm volatile("s_waitcnt vmcnt(0)" ::: "memory");
    __syncthreads();
    if (threadIdx.x == 0) {
        __hip_atomic_fetch_add(&base[(b & 15) * 16], 1u,
                               __ATOMIC_RELAXED, __HIP_MEMORY_SCOPE_SYSTEM);
        for (;;) {
            unsigned tot = 0;
#pragma unroll
            for (int i = 0; i < 16; ++i)
                tot += __hip_atomic_load(&base[i * 16],
                                         __ATOMIC_RELAXED, __HIP_MEMORY_SCOPE_SYSTEM);
            if (tot >= target) break;
            __builtin_amdgcn_s_sleep(1);
        }
    }
    __syncthreads();
}

// One wave: TWO-PASS log2-LSE for 4 rows over 2048 columns (1024 pairs).
// Pass A: exact row max (verified R12 structure, no spill at 52 VGPR).
// Pass B: recompute a; per-row wave-level SKIP — with eps=1e-4 only ~0.1%
// of terms exceed m-120; all others are exact 0.0f in f32, so skipping
// them is bit-identical. Only surviving (row, pair) slots pay exp2.
template<bool ISU>
__device__ __forceinline__ void run_task(
    const float4* __restrict__ cpA, const float4* __restrict__ cpB,
    const float*  __restrict__ rAf, const float*  __restrict__ rBf,
    int r0g, int half, int lane, float scale, float2* part2, int lr0)
{
    v2f xs0[4], xs1[4], xs2[4];
#pragma unroll
    for (int r = 0; r < 4; ++r) {
        const int rr = r0g + r;
        const int pb4 = (rr >> 1) * 4, c0 = rr & 1;
        float xv = rAf[pb4 + c0] * scale;
        float yv = rAf[pb4 + 2 + c0] * scale;
        float zv = rBf[pb4 + c0] * scale;
        xs0[r] = (v2f){xv, xv};
        xs1[r] = (v2f){yv, yv};
        xs2[r] = (v2f){zv, zv};
    }
    const int pbase = half * 1024 + lane;
    const float4* cA = cpA + pbase;
    const float4* cB = cpB + pbase;

    // ---- Pass A: exact per-row max over this half ----
    float m[4] = {-1e30f, -1e30f, -1e30f, -1e30f};
#pragma unroll 2
    for (int i = 0; i < 16; ++i) {
        const float4 a4 = cA[i * 64];
        const float4 b4 = cB[i * 64];
        const v2f xx = {a4.x, a4.y}, yy = {a4.z, a4.w};
        const v2f zz = {b4.x, b4.y}, gg = {b4.z, b4.w};
#pragma unroll
        for (int r = 0; r < 4; ++r) {
            v2f a01 = pk_fma(xs2[r], zz, gg);
            a01 = pk_fma(xs1[r], yy, a01);
            a01 = pk_fma(xs0[r], xx, a01);
            if (ISU) {
                const int rr = r0g + r;
                if (pbase + i * 64 == (rr >> 1)) {
                    if (rr & 1) a01.y = -1e30f; else a01.x = -1e30f;
                }
            }
            m[r] = max3f(m[r], a01.x, a01.y);
        }
    }
    // wave-wide max: 4 DPP levels (VALU) + 2 shfl (lanes 16, 32)
#pragma unroll
    for (int r = 0; r < 4; ++r) {
        m[r] = fmaxf(m[r], dppf<0xB1>(m[r]));
        m[r] = fmaxf(m[r], dppf<0x4E>(m[r]));
        m[r] = fmaxf(m[r], dppf<0x141>(m[r]));
        m[r] = fmaxf(m[r], dppf<0x140>(m[r]));
        m[r] = fmaxf(m[r], __shfl_xor(m[r], 16, 64));
        m[r] = fmaxf(m[r], __shfl_xor(m[r], 32, 64));
    }
    float thr[4];
    v2f nm[4];
#pragma unroll
    for (int r = 0; r < 4; ++r) {
        thr[r] = m[r] - 120.0f;                 // below this, exp2 == 0.0f exactly
        nm[r] = (v2f){-m[r], -m[r]};
    }

    // ---- Pass B: recompute; skip (row, pair) windows with no live term ----
    float s[4] = {0.0f, 0.0f, 0.0f, 0.0f};
#pragma unroll 1
    for (int i = 0; i < 16; ++i) {
        const float4 a4 = cA[i * 64];
        const float4 b4 = cB[i * 64];
        const v2f xx = {a4.x, a4.y}, yy = {a4.z, a4.w};
        const v2f zz = {b4.x, b4.y}, gg = {b4.z, b4.w};
#pragma unroll
        for (int r = 0; r < 4; ++r) {
            v2f a01 = pk_fma(xs2[r], zz, gg);
            a01 = pk_fma(xs1[r], yy, a01);
            a01 = pk_fma(xs0[r], xx, a01);
            if (ISU) {
                const int rr = r0g + r;
                if (pbase + i * 64 == (rr >> 1)) {
                    if (rr & 1) a01.y = -1e30f; else a01.x = -1e30f;
                }
            }
            float t = fmaxf(a01.x, a01.y);
            if (__any(t > thr[r])) {            // wave-uniform branch
                v2f d = pk_add(a01, nm[r]);
                s[r] += fexp2(d.x);
                s[r] += fexp2(d.y);
            }
        }
    }
    // ---- DPP sum to 8-lane partials (m already wave-uniform) ----
#pragma unroll
    for (int r = 0; r < 4; ++r) {
        float ssv = s[r];
        ssv += dppf<0xB1>(ssv);
        ssv += dppf<0x4E>(ssv);
        ssv += dppf<0x141>(ssv);
        if ((lane & 7) == 0)
            part2[(lr0 + r) * 16 + half * 8 + (lane >> 3)] = make_float2(m[r], ssv);
    }
}

__global__ void sink_init(const float* __restrict__ xin, const float* __restrict__ yin,
                          float* __restrict__ ws) {
    int t = blockIdx.x * blockDim.x + threadIdx.x;
    if (t < NPT) {
        gstore(ws + WF + t, 0.0f);
        gstore(ws + WG + t, 0.0f);
        gstore(ws + WPX0 + t, 0.0f);
        gstore(ws + WPY0 + t, 0.0f);
        float x0 = xin[3 * t], y0 = xin[3 * t + 1], z0 = xin[3 * t + 2];
        ws[WCNX + t] = 0.5f * (x0 * x0 + y0 * y0 + z0 * z0);
        float4 v = ((const float4*)yin)[t];
        ws[WCNY + t] = 0.5f * (v.x * v.x + v.y * v.y + v.z * v.z);
    }
    if (t < 512) {
        __hip_atomic_store((unsigned*)(ws + WCTR) + t, 0u,
                           __ATOMIC_RELAXED, __HIP_MEMORY_SCOPE_SYSTEM);
    }
}

__global__ __launch_bounds__(NTHR)
__attribute__((amdgpu_waves_per_eu(4, 4)))
void sink_main(
    const float* __restrict__ xin, const float* __restrict__ yin,
    float* __restrict__ ws, float* __restrict__ out)
{
    extern __shared__ float smem[];
    float4* pAx = (float4*)smem;
    float4* pBx = (float4*)(smem + 8192);
    float4* pAy = (float4*)(smem + 16384);
    float4* pBy = (float4*)(smem + 24576);
    float2* part2 = (float2*)(smem + 32768);

    float* f    = ws + WF;
    float* g    = ws + WG;
    float* px0  = ws + WPX0;
    float* px1  = ws + WPX1;
    float* py0  = ws + WPY0;
    float* py1  = ws + WPY1;
    float* ffin = ws + WFFIN;
    float* fxv  = ws + WFXV;
    float* fyv  = ws + WFYV;
    float* uls  = ws + WULS;
    unsigned* ctrA = (unsigned*)(ws + WCTR);
    unsigned* ctrB = (unsigned*)(ws + WCTR) + 256;
    const float* cnx = ws + WCNX;
    const float* cny = ws + WCNY;

    const int tid  = threadIdx.x;
    const int b    = blockIdx.x;
    const int wave = tid >> 6;
    const int lane = tid & 63;
    unsigned* cbarrier = (b < 128) ? ctrA : ctrB;

    // Stage point clouds into pair-packed LDS (G slots filled per step).
    const float4* yin4 = (const float4*)yin;
    for (int i = tid; i < 2048; i += NTHR) {
        float x0 = xin[6 * i + 0], y0v = xin[6 * i + 1], z0 = xin[6 * i + 2];
        float x1 = xin[6 * i + 3], y1v = xin[6 * i + 4], z1 = xin[6 * i + 5];
        pAx[i] = make_float4(x0, x1, y0v, y1v);
        pBx[i] = make_float4(z0, z1, 0.0f, 0.0f);
        float4 v0 = yin4[2 * i], v1 = yin4[2 * i + 1];
        pAy[i] = make_float4(v0.x, v1.x, v0.y, v1.y);
        pBy[i] = make_float4(v0.z, v1.z, 0.0f, 0.0f);
    }
    __syncthreads();

    for (int h = 0; h <= 40; ++h) {
        // ---- decode this block's chain for this step ----
        bool rows_x, cols_x, isU = false, avg = false;
        const float* pot; float* outp; float scale = INV_E2;
        int row0g, rows_pb;
        if (h == 0) {
            if (b < 128)      { rows_x = true;  cols_x = false; pot = g;    outp = f;    rows_pb = 32; row0g = b * 32; }
            else if (b < 192) { rows_x = true;  cols_x = true;  pot = px0;  outp = px1;  avg = true; rows_pb = 64; row0g = (b - 128) * 64; }
            else              { rows_x = true;  cols_x = true;  pot = nullptr; outp = uls; isU = true; scale = S_U; rows_pb = 64; row0g = (b - 192) * 64; }
        } else if (h == 40) {
            if (b < 128)      { rows_x = true;  cols_x = false; pot = g;    outp = ffin; rows_pb = 32; row0g = b * 32; }
            else if (b < 192) { rows_x = true;  cols_x = true;  pot = px0;  outp = fxv;  rows_pb = 64; row0g = (b - 128) * 64; }
            else              { rows_x = false; cols_x = false; pot = py0;  outp = fyv;  rows_pb = 64; row0g = (b - 192) * 64; }
        } else if (h & 1) {
            int k = (h - 1) >> 1;   // yy iteration
            if (b < 128) { rows_x = false; cols_x = true;  pot = f; outp = g; rows_pb = 32; row0g = b * 32; }
            else         { rows_x = false; cols_x = false; pot = (k & 1) ? py1 : py0; outp = (k & 1) ? py0 : py1; avg = true; rows_pb = 32; row0g = (b - 128) * 32; }
        } else {
            int k = h >> 1;         // xx iteration
            if (b < 128) { rows_x = true; cols_x = false; pot = g; outp = f; rows_pb = 32; row0g = b * 32; }
            else         { rows_x = true; cols_x = true;  pot = (k & 1) ? px1 : px0; outp = (k & 1) ? px0 : px1; avg = true; rows_pb = 32; row0g = (b - 128) * 32; }
        }

        // ---- restage G pair (pB[].zw): (pot - cn) * scale ----
        float4* cpA = cols_x ? pAx : pAy;
        float4* cpB = cols_x ? pBx : pBy;
        const float* ccn = cols_x ? cnx : cny;
        for (int p = tid; p < 2048; p += NTHR) {
            float2 cn2 = ((const float2*)ccn)[p];
            float pv0 = pot ? gload(pot + 2 * p)     : 0.0f;
            float pv1 = pot ? gload(pot + 2 * p + 1) : 0.0f;
            ((float2*)&cpB[p])[1] = make_float2((pv0 - cn2.x) * scale,
                                                (pv1 - cn2.y) * scale);
        }
        __syncthreads();

        // ---- wave tasks: 4 rows x 2048 cols each ----
        const float* rAf = (const float*)(rows_x ? pAx : pAy);
        const float* rBf = (const float*)(rows_x ? pBx : pBy);
        const int ntask = rows_pb >> 1;          // (rows_pb/4 groups) x 2 halves
        for (int t = wave; t < ntask; t += 16) {
            int grp = t >> 1, half = t & 1;
            int lr0 = grp << 2;
            int r0g = row0g + lr0;
            if (isU) run_task<true >(cpA, cpB, rAf, rBf, r0g, half, lane, scale, part2, lr0);
            else     run_task<false>(cpA, cpB, rAf, rBf, r0g, half, lane, scale, part2, lr0);
        }
        __syncthreads();

        // ---- finalize: merge 16 partials (max tree + pipelined exp2 sum) ----
        const float* rcn = rows_x ? cnx : cny;
        if (tid < rows_pb) {
            float2 pv2[16];
#pragma unroll
            for (int q = 0; q < 16; ++q) pv2[q] = part2[tid * 16 + q];
            float mm = pv2[0].x;
#pragma unroll
            for (int q = 1; q < 15; q += 2) mm = max3f(mm, pv2[q].x, pv2[q + 1].x);
            mm = fmaxf(mm, pv2[15].x);
            float ss = 0.0f;
#pragma unroll
            for (int q = 0; q < 16; ++q) ss += pv2[q].y * fexp2(pv2[q].x - mm);
            int rg = row0g + tid;
            float rn = rcn[rg];
            float lse2 = mm + flog2(ss) - rn * scale;    // + X_i
            float val;
            if (isU) {
                val = lse2;
            } else {
                val = -E2 * (lse2 - 12.0f);               // log2(4096)=12
                if (avg) val = 0.5f * (gload(pot + rg) + val);
            }
            gstore(outp + rg, val);
        }

        group_barrier(cbarrier, 128u * (unsigned)(h + 1), b);
    }

    // ---- final reduction (block 0; must also wait for group B) ----
    if (b == 0) {
        if (tid == 0) {
            for (;;) {
                unsigned tot = 0;
#pragma unroll
                for (int i = 0; i < 16; ++i)
                    tot += __hip_atomic_load(&ctrB[i * 16],
                                             __ATOMIC_RELAXED, __HIP_MEMORY_SCOPE_SYSTEM);
                if (tot >= 128u * 41u) break;
                __builtin_amdgcn_s_sleep(1);
            }
        }
        __syncthreads();

        float sf = 0.f, sg = 0.f, sx = 0.f, sy = 0.f, um = -1e30f, us = 0.f;
        for (int i = tid; i < NPT; i += NTHR) {
            sf += gload(ffin + i); sg += gload(g + i);
            sx += gload(fxv + i);  sy += gload(fyv + i);
            float v = gload(uls + i);
            float mn = fmaxf(um, v);
            us = us * fexp2(um - mn) + fexp2(v - mn);
            um = mn;
        }
#pragma unroll
        for (int off = 1; off < 64; off <<= 1) {
            sf += __shfl_xor(sf, off, 64);
            sg += __shfl_xor(sg, off, 64);
            sx += __shfl_xor(sx, off, 64);
            sy += __shfl_xor(sy, off, 64);
            float mo = __shfl_xor(um, off, 64);
            float so = __shfl_xor(us, off, 64);
            float mn = fmaxf(um, mo);
            us = us * fexp2(um - mn) + so * fexp2(mo - mn);
            um = mn;
        }
        __syncthreads();
        if (lane == 0) {
            float* red = smem;
            red[wave * 6 + 0] = sf; red[wave * 6 + 1] = sg; red[wave * 6 + 2] = sx;
            red[wave * 6 + 3] = sy; red[wave * 6 + 4] = um; red[wave * 6 + 5] = us;
        }
        __syncthreads();
        if (tid == 0) {
            float* red = smem;
            float Sf = 0, Sg = 0, Sx = 0, Sy = 0, Um = -1e30f, Us = 0;
            for (int w = 0; w < 16; ++w) {
                Sf += red[w * 6 + 0]; Sg += red[w * 6 + 1];
                Sx += red[w * 6 + 2]; Sy += red[w * 6 + 3];
                float mo = red[w * 6 + 4], so = red[w * 6 + 5];
                float mn = fmaxf(Um, mo);
                Us = Us * fexp2(Um - mn) + so * fexp2(mo - mn);
                Um = mn;
            }
            float mean = (Sf + Sg - Sx - Sy) * (1.0f / 4096.0f);
            float U = LN2F * (Um + flog2(Us)) - logf(4096.0f * 4095.0f);
            out[0] = mean + U;
        }
    }
}

extern "C" void kernel_launch(void* const* d_in, const int* in_sizes, int n_in,
                              void* d_out, int out_size, void* d_ws, size_t ws_size,
                              hipStream_t stream) {
    const float* x = (const float*)d_in[0];
    const float* y = (const float*)d_in[1];
    float* ws  = (float*)d_ws;
    float* out = (float*)d_out;

    (void)hipFuncSetAttribute((const void*)sink_main,
                              hipFuncAttributeMaxDynamicSharedMemorySize, SMEM_BYTES);

    sink_init<<<4, 1024, 0, stream>>>(x, y, ws);
    sink_main<<<NBLK, NTHR, SMEM_BYTES, stream>>>(x, y, ws, out);
}

// Round 15
// 482.601 us; speedup vs baseline: 1.2531x; 1.2531x over previous
//
#include <hip/hip_runtime.h>

#define NPT  4096
#define NBLK 256
#define NTHR 1024

constexpr float EPSV   = 1e-4f;
constexpr float LN2F   = 0.69314718055994531f;
constexpr float E2     = EPSV * LN2F;          // eps*ln2
constexpr float INV_E2 = 1.0f / E2;            // 1/(eps*ln2)
constexpr float S_U    = 4.0f / LN2F;          // uniformity scale

// LDS layout (floats), column-PAIR packed for v_pk_*_f32 (R9-verified):
//   pAx : float4[2048] [0,8192)      (x0,x1,y0,y1) of x-point pairs
//   pBx : float4[2048] [8192,16384)  (z0,z1,G0,G1) of x-point pairs
//   pAy : float4[2048] [16384,24576) (x0,x1,y0,y1) of y-point pairs
//   pBy : float4[2048] [24576,32768) (z0,z1,G0,G1) of y-point pairs
//   part2: float2[1024] [32768,34816) per-row (m,s) partials
#define SMEM_FLOATS 34816
#define SMEM_BYTES  (SMEM_FLOATS * 4)

// ws float offsets
#define WF     0
#define WG     4096
#define WPX0   8192
#define WPX1   12288
#define WPY0   16384
#define WPY1   20480
#define WFFIN  24576
#define WFXV   28672
#define WFYV   32768
#define WULS   36864
#define WCTR   40960    // 512 uints: arrival counters (2 groups x 16 x stride 16)
#define WREL   41472    // uints: relA at +0, relB at +64
#define WCNX   41984    // float[4096]: 0.5*||x_i||^2
#define WCNY   46080    // float[4096]: 0.5*||y_j||^2
// pre-scaled column potentials: G[j] = (pot[j] - cn[j]) * INV_E2
#define WFG    50176
#define WGG    54272
#define WPXG0  58368
#define WPXG1  62464
#define WPYG0  66560
#define WPYG1  70656    // end 74752 floats = 299 KB (R7-proven footprint)

typedef float v2f __attribute__((ext_vector_type(2)));

__device__ __forceinline__ float fexp2(float x) { return __builtin_amdgcn_exp2f(x); }
__device__ __forceinline__ float flog2(float x) { return __builtin_amdgcn_logf(x); }

__device__ __forceinline__ v2f pk_fma(v2f a, v2f b, v2f c) {
    v2f d;
    asm("v_pk_fma_f32 %0, %1, %2, %3" : "=v"(d) : "v"(a), "v"(b), "v"(c));
    return d;
}
__device__ __forceinline__ v2f pk_add(v2f a, v2f b) {
    v2f d;
    asm("v_pk_add_f32 %0, %1, %2" : "=v"(d) : "v"(a), "v"(b));
    return d;
}
__device__ __forceinline__ float max3f(float a, float b, float c) {
    float d;
    asm("v_max3_f32 %0, %1, %2, %3" : "=v"(d) : "v"(a), "v"(b), "v"(c));
    return d;
}

// VALU-only cross-lane via DPP: xor1, xor2, row_half_mirror.
template<int CTRL>
__device__ __forceinline__ float dppf(float x) {
    return __int_as_float(__builtin_amdgcn_update_dpp(
        __float_as_int(x), __float_as_int(x), CTRL, 0xF, 0xF, false));
}

// system-scope (sc0 sc1) relaxed accessors: bypass non-coherent XCD L2s.
__device__ __forceinline__ float gload(const float* p) {
    return __hip_atomic_load(p, __ATOMIC_RELAXED, __HIP_MEMORY_SCOPE_SYSTEM);
}
__device__ __forceinline__ void gstore(float* p, float v) {
    __hip_atomic_store(p, v, __ATOMIC_RELAXED, __HIP_MEMORY_SCOPE_SYSTEM);
}
__device__ __forceinline__ float2 gload2(const float* p) {
    unsigned long long raw = __hip_atomic_load((const unsigned long long*)p,
                                               __ATOMIC_RELAXED, __HIP_MEMORY_SCOPE_SYSTEM);
    union { unsigned long long u; float2 f2; } cv; cv.u = raw;
    return cv.f2;
}

// Release-flag group barrier (128 blocks/group): lead block (bb==0) polls the
// 16 arrival counters then publishes a monotonic release word; the other 127
// blocks poll ONE line instead of 16. Arrivals happen after each block's
// global stores drained (vmcnt(0) + syncthreads), release follows all
// arrivals -> same ordering guarantees as the R9 barrier.
__device__ __forceinline__ void group_barrier(unsigned* ctr, unsigned* rel,
                                              unsigned tcnt, unsigned trel, int bb) {
    asm volatile("s_waitcnt vmcnt(0)" ::: "memory");
    __syncthreads();
    if (threadIdx.x == 0) {
        __hip_atomic_fetch_add(&ctr[(bb & 15) * 16], 1u,
                               __ATOMIC_RELAXED, __HIP_MEMORY_SCOPE_SYSTEM);
        if (bb == 0) {
            for (;;) {
                unsigned tot = 0;
#pragma unroll
                for (int i = 0; i < 16; ++i)
                    tot += __hip_atomic_load(&ctr[i * 16],
                                             __ATOMIC_RELAXED, __HIP_MEMORY_SCOPE_SYSTEM);
                if (tot >= tcnt) break;
                __builtin_amdgcn_s_sleep(1);
            }
            __hip_atomic_store(rel, trel, __ATOMIC_RELAXED, __HIP_MEMORY_SCOPE_SYSTEM);
        } else {
            while (__hip_atomic_load(rel, __ATOMIC_RELAXED, __HIP_MEMORY_SCOPE_SYSTEM) < trel)
                __builtin_amdgcn_s_sleep(1);
        }
    }
    __syncthreads();
}

// One wave: log2-LSE for 2 rows over 2048 columns (1024 pairs, one half).
// R9-verified chunked pk-f32 inner loop (av[2][4] v2f, 52 VGPR, no spill)
// + DPP-8 VALU-only reduction tail. UNCHANGED from R9.
template<bool ISU>
__device__ __forceinline__ void run_task(
    const float4* __restrict__ cpA, const float4* __restrict__ cpB,
    const float*  __restrict__ rAf, const float*  __restrict__ rBf,
    int r0g, int half, int lane, float scale, float2* part2, int lr0)
{
    v2f xs0[2], xs1[2], xs2[2];
#pragma unroll
    for (int r = 0; r < 2; ++r) {
        const int rr = r0g + r;
        const int pb4 = (rr >> 1) * 4, c0 = rr & 1;
        float xv = rAf[pb4 + c0] * scale;
        float yv = rAf[pb4 + 2 + c0] * scale;
        float zv = rBf[pb4 + c0] * scale;
        xs0[r] = (v2f){xv, xv};
        xs1[r] = (v2f){yv, yv};
        xs2[r] = (v2f){zv, zv};
    }
    float m[2], s[2];
    const int pbase = half * 1024 + lane;
    const float4* colA = cpA + pbase;
    const float4* colB = cpB + pbase;

#pragma unroll
    for (int chunk = 0; chunk < 4; ++chunk) {
        v2f av[2][4];
        float mc[2] = {-1e30f, -1e30f};
#pragma unroll
        for (int k = 0; k < 4; ++k) {
            const float4 a4 = colA[(chunk * 4 + k) * 64];
            const float4 b4 = colB[(chunk * 4 + k) * 64];
            const v2f xx = {a4.x, a4.y}, yy = {a4.z, a4.w};
            const v2f zz = {b4.x, b4.y}, gg = {b4.z, b4.w};
#pragma unroll
            for (int r = 0; r < 2; ++r) {
                v2f a01 = pk_fma(xs2[r], zz, gg);
                a01 = pk_fma(xs1[r], yy, a01);
                a01 = pk_fma(xs0[r], xx, a01);
                if (ISU) {
                    const int p = pbase + (chunk * 4 + k) * 64;
                    const int rr = r0g + r;
                    if (p == (rr >> 1)) {
                        if (rr & 1) a01.y = -1e30f; else a01.x = -1e30f;
                    }
                }
                av[r][k] = a01;
                mc[r] = max3f(mc[r], a01.x, a01.y);
            }
        }
#pragma unroll
        for (int r = 0; r < 2; ++r) {
            const float nm = -mc[r];
            v2f mcn = {nm, nm};
            float sA = 0.0f, sB = 0.0f;
#pragma unroll
            for (int k = 0; k < 4; ++k) {
                v2f d = pk_add(av[r][k], mcn);
                sA += fexp2(d.x);
                sB += fexp2(d.y);
            }
            const float sc_ = sA + sB;
            if (chunk == 0) { m[r] = mc[r]; s[r] = sc_; }
            else {
                float dd = m[r] - mc[r];
                float e = fexp2(-fabsf(dd));
                float bigs   = (dd >= 0.0f) ? s[r] : sc_;
                float smalls = (dd >= 0.0f) ? sc_  : s[r];
                s[r] = fmaf(smalls, e, bigs);
                m[r] = fmaxf(m[r], mc[r]);
            }
        }
    }
#pragma unroll
    for (int r = 0; r < 2; ++r) {
        const float ml = m[r];
        float mm = m[r];
        mm = fmaxf(mm, dppf<0xB1>(mm));
        mm = fmaxf(mm, dppf<0x4E>(mm));
        mm = fmaxf(mm, dppf<0x141>(mm));
        float ssv = s[r] * fexp2(ml - mm);
        ssv += dppf<0xB1>(ssv);
        ssv += dppf<0x4E>(ssv);
        ssv += dppf<0x141>(ssv);
        if ((lane & 7) == 0)
            part2[(lr0 + r) * 16 + half * 8 + (lane >> 3)] = make_float2(mm, ssv);
    }
}

__global__ void sink_init(const float* __restrict__ xin, const float* __restrict__ yin,
                          float* __restrict__ ws) {
    int t = blockIdx.x * blockDim.x + threadIdx.x;
    if (t < NPT) {
        gstore(ws + WF + t, 0.0f);
        gstore(ws + WG + t, 0.0f);
        gstore(ws + WPX0 + t, 0.0f);
        gstore(ws + WPY0 + t, 0.0f);
        float x0 = xin[3 * t], y0 = xin[3 * t + 1], z0 = xin[3 * t + 2];
        float cnx = 0.5f * (x0 * x0 + y0 * y0 + z0 * z0);
        float4 v = ((const float4*)yin)[t];
        float cny = 0.5f * (v.x * v.x + v.y * v.y + v.z * v.z);
        ws[WCNX + t] = cnx;
        ws[WCNY + t] = cny;
        // initial scaled potentials (pot = 0)
        gstore(ws + WGG   + t, -cny * INV_E2);   // g over y
        gstore(ws + WPXG0 + t, -cnx * INV_E2);   // px0 over x
        gstore(ws + WPYG0 + t, -cny * INV_E2);   // py0 over y
    }
    if (t < 640) {      // arrival counters + release flags
        __hip_atomic_store((unsigned*)(ws + WCTR) + t, 0u,
                           __ATOMIC_RELAXED, __HIP_MEMORY_SCOPE_SYSTEM);
    }
}

__global__ __launch_bounds__(NTHR)
__attribute__((amdgpu_waves_per_eu(4, 4)))
void sink_main(
    const float* __restrict__ xin, const float* __restrict__ yin,
    float* __restrict__ ws, float* __restrict__ out)
{
    extern __shared__ float smem[];
    float4* pAx = (float4*)smem;
    float4* pBx = (float4*)(smem + 8192);
    float4* pAy = (float4*)(smem + 16384);
    float4* pBy = (float4*)(smem + 24576);
    float2* part2 = (float2*)(smem + 32768);

    float* f    = ws + WF;
    float* g    = ws + WG;
    float* px0  = ws + WPX0;
    float* px1  = ws + WPX1;
    float* py0  = ws + WPY0;
    float* py1  = ws + WPY1;
    float* ffin = ws + WFFIN;
    float* fxv  = ws + WFXV;
    float* fyv  = ws + WFYV;
    float* uls  = ws + WULS;
    unsigned* ctrA = (unsigned*)(ws + WCTR);
    unsigned* ctrB = (unsigned*)(ws + WCTR) + 256;
    unsigned* relA = (unsigned*)(ws + WREL);
    unsigned* relB = (unsigned*)(ws + WREL) + 64;
    const float* cnx = ws + WCNX;
    const float* cny = ws + WCNY;
    float* fG   = ws + WFG;
    float* gG   = ws + WGG;
    float* pxG0 = ws + WPXG0;
    float* pxG1 = ws + WPXG1;
    float* pyG0 = ws + WPYG0;
    float* pyG1 = ws + WPYG1;

    const int tid  = threadIdx.x;
    const int b    = blockIdx.x;
    const int wave = tid >> 6;
    const int lane = tid & 63;
    const bool isA = b < 128;
    const int bb   = isA ? b : b - 128;
    unsigned* cctr = isA ? ctrA : ctrB;
    unsigned* crel = isA ? relA : relB;

    // Stage point clouds into pair-packed LDS (G slots filled per step).
    const float4* yin4 = (const float4*)yin;
    for (int i = tid; i < 2048; i += NTHR) {
        float x0 = xin[6 * i + 0], y0v = xin[6 * i + 1], z0 = xin[6 * i + 2];
        float x1 = xin[6 * i + 3], y1v = xin[6 * i + 4], z1 = xin[6 * i + 5];
        pAx[i] = make_float4(x0, x1, y0v, y1v);
        pBx[i] = make_float4(z0, z1, 0.0f, 0.0f);
        float4 v0 = yin4[2 * i], v1 = yin4[2 * i + 1];
        pAy[i] = make_float4(v0.x, v1.x, v0.y, v1.y);
        pBy[i] = make_float4(v0.z, v1.z, 0.0f, 0.0f);
    }
    __syncthreads();

    for (int h = 0; h <= 40; ++h) {
        // ---- decode this block's chain for this step ----
        bool rows_x, cols_x, isU = false, avg = false;
        const float* pot; const float* potG; float* outp; float* outpG;
        float scale = INV_E2;
        int row0g, rows_pb;
        if (h == 0) {
            if (b < 128)      { rows_x = true;  cols_x = false; pot = g;   potG = gG;   outp = f;   outpG = fG;   rows_pb = 32; row0g = b * 32; }
            else if (b < 192) { rows_x = true;  cols_x = true;  pot = px0; potG = pxG0; outp = px1; outpG = pxG1; avg = true; rows_pb = 64; row0g = (b - 128) * 64; }
            else              { rows_x = true;  cols_x = true;  pot = nullptr; potG = nullptr; outp = uls; outpG = nullptr; isU = true; scale = S_U; rows_pb = 64; row0g = (b - 192) * 64; }
        } else if (h == 40) {
            if (b < 128)      { rows_x = true;  cols_x = false; pot = g;   potG = gG;   outp = ffin; outpG = nullptr; rows_pb = 32; row0g = b * 32; }
            else if (b < 192) { rows_x = true;  cols_x = true;  pot = px0; potG = pxG0; outp = fxv;  outpG = nullptr; rows_pb = 64; row0g = (b - 128) * 64; }
            else              { rows_x = false; cols_x = false; pot = py0; potG = pyG0; outp = fyv;  outpG = nullptr; rows_pb = 64; row0g = (b - 192) * 64; }
        } else if (h & 1) {
            int k = (h - 1) >> 1;   // yy iteration
            if (b < 128) { rows_x = false; cols_x = true;  pot = f; potG = fG; outp = g; outpG = gG; rows_pb = 32; row0g = b * 32; }
            else         { rows_x = false; cols_x = false;
                           pot  = (k & 1) ? py1  : py0;  potG  = (k & 1) ? pyG1 : pyG0;
                           outp = (k & 1) ? py0  : py1;  outpG = (k & 1) ? pyG0 : pyG1;
                           avg = true; rows_pb = 32; row0g = (b - 128) * 32; }
        } else {
            int k = h >> 1;         // xx iteration
            if (b < 128) { rows_x = true; cols_x = false; pot = g; potG = gG; outp = f; outpG = fG; rows_pb = 32; row0g = b * 32; }
            else         { rows_x = true; cols_x = true;
                           pot  = (k & 1) ? px1  : px0;  potG  = (k & 1) ? pxG1 : pxG0;
                           outp = (k & 1) ? px0  : px1;  outpG = (k & 1) ? pxG0 : pxG1;
                           avg = true; rows_pb = 32; row0g = (b - 128) * 32; }
        }

        // ---- restage G pair (pB[].zw): single 8B load of pre-scaled G ----
        float4* cpA = cols_x ? pAx : pAy;
        float4* cpB = cols_x ? pBx : pBy;
        const float* ccn = cols_x ? cnx : cny;
        for (int p = tid; p < 2048; p += NTHR) {
            float2 g2;
            if (isU) {
                float2 cn2 = ((const float2*)ccn)[p];
                g2 = make_float2(-cn2.x * S_U, -cn2.y * S_U);
            } else {
                g2 = gload2(potG + 2 * p);
            }
            ((float2*)&cpB[p])[1] = g2;
        }
        __syncthreads();

        // ---- wave tasks: 2 rows x 2048 cols each (R9-verified) ----
        const float* rAf = (const float*)(rows_x ? pAx : pAy);
        const float* rBf = (const float*)(rows_x ? pBx : pBy);
        const int ntask = rows_pb;
        for (int t = wave; t < ntask; t += 16) {
            int grp = t >> 1, half = t & 1;
            int lr0 = grp << 1;
            int r0g = row0g + lr0;
            if (isU) run_task<true >(cpA, cpB, rAf, rBf, r0g, half, lane, scale, part2, lr0);
            else     run_task<false>(cpA, cpB, rAf, rBf, r0g, half, lane, scale, part2, lr0);
        }
        __syncthreads();

        // ---- finalize: merge 16 partials; write raw AND pre-scaled G ----
        const float* rcn = rows_x ? cnx : cny;
        if (tid < rows_pb) {
            float2 pv2[16];
#pragma unroll
            for (int q = 0; q < 16; ++q) pv2[q] = part2[tid * 16 + q];
            float mm = pv2[0].x;
#pragma unroll
            for (int q = 1; q < 15; q += 2) mm = max3f(mm, pv2[q].x, pv2[q + 1].x);
            mm = fmaxf(mm, pv2[15].x);
            float ss = 0.0f;
#pragma unroll
            for (int q = 0; q < 16; ++q) ss += pv2[q].y * fexp2(pv2[q].x - mm);
            int rg = row0g + tid;
            float rn = rcn[rg];
            float lse2 = mm + flog2(ss) - rn * scale;    // + X_i
            float val;
            if (isU) {
                val = lse2;
            } else {
                val = -E2 * (lse2 - 12.0f);               // log2(4096)=12
                if (avg) val = 0.5f * (gload(pot + rg) + val);
            }
            gstore(outp + rg, val);
            if (outpG) gstore(outpG + rg, (val - rn) * INV_E2);
        }

        group_barrier(cctr, crel, 128u * (unsigned)(h + 1), (unsigned)(h + 1), bb);
    }

    // ---- final reduction (block 0; must also wait for group B) ----
    if (b == 0) {
        if (tid == 0) {
            while (__hip_atomic_load(relB, __ATOMIC_RELAXED, __HIP_MEMORY_SCOPE_SYSTEM) < 41u)
                __builtin_amdgcn_s_sleep(1);
        }
        __syncthreads();

        float sf = 0.f, sg = 0.f, sx = 0.f, sy = 0.f, um = -1e30f, us = 0.f;
        for (int i = tid; i < NPT; i += NTHR) {
            sf += gload(ffin + i); sg += gload(g + i);
            sx += gload(fxv + i);  sy += gload(fyv + i);
            float v = gload(uls + i);
            float mn = fmaxf(um, v);
            us = us * fexp2(um - mn) + fexp2(v - mn);
            um = mn;
        }
#pragma unroll
        for (int off = 1; off < 64; off <<= 1) {
            sf += __shfl_xor(sf, off, 64);
            sg += __shfl_xor(sg, off, 64);
            sx += __shfl_xor(sx, off, 64);
            sy += __shfl_xor(sy, off, 64);
            float mo = __shfl_xor(um, off, 64);
            float so = __shfl_xor(us, off, 64);
            float mn = fmaxf(um, mo);
            us = us * fexp2(um - mn) + so * fexp2(mo - mn);
            um = mn;
        }
        __syncthreads();
        if (lane == 0) {
            float* red = smem;
            red[wave * 6 + 0] = sf; red[wave * 6 + 1] = sg; red[wave * 6 + 2] = sx;
            red[wave * 6 + 3] = sy; red[wave * 6 + 4] = um; red[wave * 6 + 5] = us;
        }
        __syncthreads();
        if (tid == 0) {
            float* red = smem;
            float Sf = 0, Sg = 0, Sx = 0, Sy = 0, Um = -1e30f, Us = 0;
            for (int w = 0; w < 16; ++w) {
                Sf += red[w * 6 + 0]; Sg += red[w * 6 + 1];
                Sx += red[w * 6 + 2]; Sy += red[w * 6 + 3];
                float mo = red[w * 6 + 4], so = red[w * 6 + 5];
                float mn = fmaxf(Um, mo);
                Us = Us * fexp2(Um - mn) + so * fexp2(mo - mn);
                Um = mn;
            }
            float mean = (Sf + Sg - Sx - Sy) * (1.0f / 4096.0f);
            float U = LN2F * (Um + flog2(Us)) - logf(4096.0f * 4095.0f);
            out[0] = mean + U;
        }
    }
}

extern "C" void kernel_launch(void* const* d_in, const int* in_sizes, int n_in,
                              void* d_out, int out_size, void* d_ws, size_t ws_size,
                              hipStream_t stream) {
    const float* x = (const float*)d_in[0];
    const float* y = (const float*)d_in[1];
    float* ws  = (float*)d_ws;
    float* out = (float*)d_out;

    (void)hipFuncSetAttribute((const void*)sink_main,
                              hipFuncAttributeMaxDynamicSharedMemorySize, SMEM_BYTES);

    sink_init<<<4, 1024, 0, stream>>>(x, y, ws);
    sink_main<<<NBLK, NTHR, SMEM_BYTES, stream>>>(x, y, ws, out);
}

// Round 16
// 463.945 us; speedup vs baseline: 1.3035x; 1.0402x over previous
//
#include <hip/hip_runtime.h>

#define NPT  4096
#define NBLK 256
#define NTHR 1024

constexpr float EPSV   = 1e-4f;
constexpr float LN2F   = 0.69314718055994531f;
constexpr float E2     = EPSV * LN2F;          // eps*ln2
constexpr float INV_E2 = 1.0f / E2;            // 1/(eps*ln2)
constexpr float S_U    = 4.0f / LN2F;          // uniformity scale

// LDS layout (floats), column-PAIR packed for v_pk_*_f32 (R9/R15-verified):
//   pAx : float4[2048] [0,8192)      (x0,x1,y0,y1) of x-point pairs
//   pBx : float4[2048] [8192,16384)  (z0,z1,G0,G1) of x-point pairs
//   pAy : float4[2048] [16384,24576) (x0,x1,y0,y1) of y-point pairs
//   pBy : float4[2048] [24576,32768) (z0,z1,G0,G1) of y-point pairs
//   part2: float2[1024] [32768,34816) per-row (m,s) partials
#define SMEM_FLOATS 34816
#define SMEM_BYTES  (SMEM_FLOATS * 4)

// ws float offsets
#define WF     0
#define WG     4096
#define WPX0   8192
#define WPX1   12288
#define WPY0   16384
#define WPY1   20480
#define WFFIN  24576
#define WFXV   28672
#define WFYV   32768
#define WULS   36864
#define WCTR   40960    // 512 uints: arrival counters
#define WREL   41472    // uints: relA at +0, relB at +64
#define WCNX   41984    // float[4096]: 0.5*||x_i||^2
#define WCNY   46080    // float[4096]: 0.5*||y_j||^2
// pre-scaled column potentials: G[j] = (pot[j] - cn[j]) * INV_E2
#define WFG    50176
#define WGG    54272
#define WPXG0  58368
#define WPXG1  62464
#define WPYG0  66560
#define WPYG1  70656

typedef float v2f __attribute__((ext_vector_type(2)));

__device__ __forceinline__ float fexp2(float x) { return __builtin_amdgcn_exp2f(x); }
__device__ __forceinline__ float flog2(float x) { return __builtin_amdgcn_logf(x); }

// op_sel-broadcast pk_fma: one v2f 'a' holds TWO rows' coefficients.
// _lo: both halves use a.lo  (row in .x slot); _hi: both halves use a.hi.
__device__ __forceinline__ v2f pk_fma_lo(v2f a, v2f b, v2f c) {
    v2f d;
    asm("v_pk_fma_f32 %0, %1, %2, %3 op_sel:[0,0,0] op_sel_hi:[0,1,1]"
        : "=v"(d) : "v"(a), "v"(b), "v"(c));
    return d;
}
__device__ __forceinline__ v2f pk_fma_hi(v2f a, v2f b, v2f c) {
    v2f d;
    asm("v_pk_fma_f32 %0, %1, %2, %3 op_sel:[1,0,0] op_sel_hi:[1,1,1]"
        : "=v"(d) : "v"(a), "v"(b), "v"(c));
    return d;
}
__device__ __forceinline__ v2f pk_add(v2f a, v2f b) {
    v2f d;
    asm("v_pk_add_f32 %0, %1, %2" : "=v"(d) : "v"(a), "v"(b));
    return d;
}
__device__ __forceinline__ float max3f(float a, float b, float c) {
    float d;
    asm("v_max3_f32 %0, %1, %2, %3" : "=v"(d) : "v"(a), "v"(b), "v"(c));
    return d;
}

// VALU-only cross-lane via DPP: xor1, xor2, row_half_mirror.
template<int CTRL>
__device__ __forceinline__ float dppf(float x) {
    return __int_as_float(__builtin_amdgcn_update_dpp(
        __float_as_int(x), __float_as_int(x), CTRL, 0xF, 0xF, false));
}

// system-scope (sc0 sc1) relaxed accessors: bypass non-coherent XCD L2s.
__device__ __forceinline__ float gload(const float* p) {
    return __hip_atomic_load(p, __ATOMIC_RELAXED, __HIP_MEMORY_SCOPE_SYSTEM);
}
__device__ __forceinline__ void gstore(float* p, float v) {
    __hip_atomic_store(p, v, __ATOMIC_RELAXED, __HIP_MEMORY_SCOPE_SYSTEM);
}
__device__ __forceinline__ float2 gload2(const float* p) {
    unsigned long long raw = __hip_atomic_load((const unsigned long long*)p,
                                               __ATOMIC_RELAXED, __HIP_MEMORY_SCOPE_SYSTEM);
    union { unsigned long long u; float2 f2; } cv; cv.u = raw;
    return cv.f2;
}

// Release-flag group barrier (128 blocks/group), R15-verified.
__device__ __forceinline__ void group_barrier(unsigned* ctr, unsigned* rel,
                                              unsigned tcnt, unsigned trel, int bb) {
    asm volatile("s_waitcnt vmcnt(0)" ::: "memory");
    __syncthreads();
    if (threadIdx.x == 0) {
        __hip_atomic_fetch_add(&ctr[(bb & 15) * 16], 1u,
                               __ATOMIC_RELAXED, __HIP_MEMORY_SCOPE_SYSTEM);
        if (bb == 0) {
            for (;;) {
                unsigned tot = 0;
#pragma unroll
                for (int i = 0; i < 16; ++i)
                    tot += __hip_atomic_load(&ctr[i * 16],
                                             __ATOMIC_RELAXED, __HIP_MEMORY_SCOPE_SYSTEM);
                if (tot >= tcnt) break;
                __builtin_amdgcn_s_sleep(1);
            }
            __hip_atomic_store(rel, trel, __ATOMIC_RELAXED, __HIP_MEMORY_SCOPE_SYSTEM);
        } else {
            while (__hip_atomic_load(rel, __ATOMIC_RELAXED, __HIP_MEMORY_SCOPE_SYSTEM) < trel)
                __builtin_amdgcn_s_sleep(1);
        }
    }
    __syncthreads();
}

// One wave: log2-LSE for 4 ROWS over 2048 columns (1024 pairs, one half).
// Each column-pair read ONCE for 4 rows (halves the per-CU LDS-pipe load vs
// R=2). op_sel-broadcast pk_fma keeps xs at 12 VGPR; chunk=2 (av[4][2]=16)
// + unroll-1 keeps the live set ~58 VGPR under the immovable 64 cap.
template<bool ISU>
__device__ __forceinline__ void run_task(
    const float4* __restrict__ cpA, const float4* __restrict__ cpB,
    const float*  __restrict__ rAf, const float*  __restrict__ rBf,
    int r0g, int half, int lane, float scale, float2* part2, int lr0)
{
    // rows r0g..r0g+3 = LDS pairs q, q+1 (r0g is 4-aligned)
    const int q4 = (r0g >> 1) * 4;
    v2f xsA0 = {rAf[q4 + 0] * scale, rAf[q4 + 1] * scale};   // x rows 0,1
    v2f xsA1 = {rAf[q4 + 2] * scale, rAf[q4 + 3] * scale};   // y rows 0,1
    v2f xsA2 = {rBf[q4 + 0] * scale, rBf[q4 + 1] * scale};   // z rows 0,1
    v2f xsB0 = {rAf[q4 + 4] * scale, rAf[q4 + 5] * scale};   // x rows 2,3
    v2f xsB1 = {rAf[q4 + 6] * scale, rAf[q4 + 7] * scale};   // y rows 2,3
    v2f xsB2 = {rBf[q4 + 4] * scale, rBf[q4 + 5] * scale};   // z rows 2,3

    float m[4] = {-1e30f, -1e30f, -1e30f, -1e30f};
    float s[4] = {0.0f, 0.0f, 0.0f, 0.0f};
    const int pbase = half * 1024 + lane;
    const float4* colA = cpA + pbase;
    const float4* colB = cpB + pbase;

#pragma unroll 1
    for (int c = 0; c < 8; ++c) {
        v2f av[4][2];
#pragma unroll
        for (int k = 0; k < 2; ++k) {
            const float4 a4 = colA[(c * 2 + k) * 64];
            const float4 b4 = colB[(c * 2 + k) * 64];
            const v2f xx = {a4.x, a4.y}, yy = {a4.z, a4.w};
            const v2f zz = {b4.x, b4.y}, gg = {b4.z, b4.w};
            v2f t0 = pk_fma_lo(xsA2, zz, gg);
            t0 = pk_fma_lo(xsA1, yy, t0);
            t0 = pk_fma_lo(xsA0, xx, t0);
            v2f t1 = pk_fma_hi(xsA2, zz, gg);
            t1 = pk_fma_hi(xsA1, yy, t1);
            t1 = pk_fma_hi(xsA0, xx, t1);
            v2f t2 = pk_fma_lo(xsB2, zz, gg);
            t2 = pk_fma_lo(xsB1, yy, t2);
            t2 = pk_fma_lo(xsB0, xx, t2);
            v2f t3 = pk_fma_hi(xsB2, zz, gg);
            t3 = pk_fma_hi(xsB1, yy, t3);
            t3 = pk_fma_hi(xsB0, xx, t3);
            if (ISU) {
                const int p = pbase + (c * 2 + k) * 64;
#pragma unroll
                for (int r = 0; r < 4; ++r) {
                    const int rr = r0g + r;
                    if (p == (rr >> 1)) {
                        v2f* tv = (r == 0) ? &t0 : (r == 1) ? &t1 : (r == 2) ? &t2 : &t3;
                        if (rr & 1) tv->y = -1e30f; else tv->x = -1e30f;
                    }
                }
            }
            av[0][k] = t0; av[1][k] = t1; av[2][k] = t2; av[3][k] = t3;
        }
#pragma unroll
        for (int r = 0; r < 4; ++r) {
            float mc = max3f(av[r][0].x, av[r][0].y, av[r][1].x);
            mc = fmaxf(mc, av[r][1].y);
            const float mn = fmaxf(m[r], mc);
            const float e = fexp2(m[r] - mn);     // first chunk: exp2(-inf)=0
            v2f nm2 = {-mn, -mn};
            v2f d0 = pk_add(av[r][0], nm2);
            v2f d1 = pk_add(av[r][1], nm2);
            float sc_ = fexp2(d0.x) + fexp2(d0.y) + fexp2(d1.x) + fexp2(d1.y);
            s[r] = fmaf(s[r], e, sc_);
            m[r] = mn;
        }
    }
    // ---- VALU-only DPP reduction to 8-lane partials ----
#pragma unroll
    for (int r = 0; r < 4; ++r) {
        const float ml = m[r];
        float mm = m[r];
        mm = fmaxf(mm, dppf<0xB1>(mm));
        mm = fmaxf(mm, dppf<0x4E>(mm));
        mm = fmaxf(mm, dppf<0x141>(mm));
        float ssv = s[r] * fexp2(ml - mm);
        ssv += dppf<0xB1>(ssv);
        ssv += dppf<0x4E>(ssv);
        ssv += dppf<0x141>(ssv);
        if ((lane & 7) == 0)
            part2[(lr0 + r) * 16 + half * 8 + (lane >> 3)] = make_float2(mm, ssv);
    }
}

__global__ void sink_init(const float* __restrict__ xin, const float* __restrict__ yin,
                          float* __restrict__ ws) {
    int t = blockIdx.x * blockDim.x + threadIdx.x;
    if (t < NPT) {
        gstore(ws + WF + t, 0.0f);
        gstore(ws + WG + t, 0.0f);
        gstore(ws + WPX0 + t, 0.0f);
        gstore(ws + WPY0 + t, 0.0f);
        float x0 = xin[3 * t], y0 = xin[3 * t + 1], z0 = xin[3 * t + 2];
        float cnx = 0.5f * (x0 * x0 + y0 * y0 + z0 * z0);
        float4 v = ((const float4*)yin)[t];
        float cny = 0.5f * (v.x * v.x + v.y * v.y + v.z * v.z);
        ws[WCNX + t] = cnx;
        ws[WCNY + t] = cny;
        gstore(ws + WGG   + t, -cny * INV_E2);   // g over y (pot=0)
        gstore(ws + WPXG0 + t, -cnx * INV_E2);   // px0 over x
        gstore(ws + WPYG0 + t, -cny * INV_E2);   // py0 over y
    }
    if (t < 640) {
        __hip_atomic_store((unsigned*)(ws + WCTR) + t, 0u,
                           __ATOMIC_RELAXED, __HIP_MEMORY_SCOPE_SYSTEM);
    }
}

__global__ __launch_bounds__(NTHR)
__attribute__((amdgpu_waves_per_eu(4, 4)))
void sink_main(
    const float* __restrict__ xin, const float* __restrict__ yin,
    float* __restrict__ ws, float* __restrict__ out)
{
    extern __shared__ float smem[];
    float4* pAx = (float4*)smem;
    float4* pBx = (float4*)(smem + 8192);
    float4* pAy = (float4*)(smem + 16384);
    float4* pBy = (float4*)(smem + 24576);
    float2* part2 = (float2*)(smem + 32768);

    float* f    = ws + WF;
    float* g    = ws + WG;
    float* px0  = ws + WPX0;
    float* px1  = ws + WPX1;
    float* py0  = ws + WPY0;
    float* py1  = ws + WPY1;
    float* ffin = ws + WFFIN;
    float* fxv  = ws + WFXV;
    float* fyv  = ws + WFYV;
    float* uls  = ws + WULS;
    unsigned* ctrA = (unsigned*)(ws + WCTR);
    unsigned* ctrB = (unsigned*)(ws + WCTR) + 256;
    unsigned* relA = (unsigned*)(ws + WREL);
    unsigned* relB = (unsigned*)(ws + WREL) + 64;
    const float* cnx = ws + WCNX;
    const float* cny = ws + WCNY;
    float* fG   = ws + WFG;
    float* gG   = ws + WGG;
    float* pxG0 = ws + WPXG0;
    float* pxG1 = ws + WPXG1;
    float* pyG0 = ws + WPYG0;
    float* pyG1 = ws + WPYG1;

    const int tid  = threadIdx.x;
    const int b    = blockIdx.x;
    const int wave = tid >> 6;
    const int lane = tid & 63;
    const bool isA = b < 128;
    const int bb   = isA ? b : b - 128;
    unsigned* cctr = isA ? ctrA : ctrB;
    unsigned* crel = isA ? relA : relB;

    // Stage point clouds into pair-packed LDS (G slots filled per step).
    const float4* yin4 = (const float4*)yin;
    for (int i = tid; i < 2048; i += NTHR) {
        float x0 = xin[6 * i + 0], y0v = xin[6 * i + 1], z0 = xin[6 * i + 2];
        float x1 = xin[6 * i + 3], y1v = xin[6 * i + 4], z1 = xin[6 * i + 5];
        pAx[i] = make_float4(x0, x1, y0v, y1v);
        pBx[i] = make_float4(z0, z1, 0.0f, 0.0f);
        float4 v0 = yin4[2 * i], v1 = yin4[2 * i + 1];
        pAy[i] = make_float4(v0.x, v1.x, v0.y, v1.y);
        pBy[i] = make_float4(v0.z, v1.z, 0.0f, 0.0f);
    }
    __syncthreads();

    for (int h = 0; h <= 40; ++h) {
        // ---- decode this block's chain for this step ----
        bool rows_x, cols_x, isU = false, avg = false;
        const float* pot; const float* potG; float* outp; float* outpG;
        float scale = INV_E2;
        int row0g, rows_pb;
        if (h == 0) {
            if (b < 128)      { rows_x = true;  cols_x = false; pot = g;   potG = gG;   outp = f;   outpG = fG;   rows_pb = 32; row0g = b * 32; }
            else if (b < 192) { rows_x = true;  cols_x = true;  pot = px0; potG = pxG0; outp = px1; outpG = pxG1; avg = true; rows_pb = 64; row0g = (b - 128) * 64; }
            else              { rows_x = true;  cols_x = true;  pot = nullptr; potG = nullptr; outp = uls; outpG = nullptr; isU = true; scale = S_U; rows_pb = 64; row0g = (b - 192) * 64; }
        } else if (h == 40) {
            if (b < 128)      { rows_x = true;  cols_x = false; pot = g;   potG = gG;   outp = ffin; outpG = nullptr; rows_pb = 32; row0g = b * 32; }
            else if (b < 192) { rows_x = true;  cols_x = true;  pot = px0; potG = pxG0; outp = fxv;  outpG = nullptr; rows_pb = 64; row0g = (b - 128) * 64; }
            else              { rows_x = false; cols_x = false; pot = py0; potG = pyG0; outp = fyv;  outpG = nullptr; rows_pb = 64; row0g = (b - 192) * 64; }
        } else if (h & 1) {
            int k = (h - 1) >> 1;   // yy iteration
            if (b < 128) { rows_x = false; cols_x = true;  pot = f; potG = fG; outp = g; outpG = gG; rows_pb = 32; row0g = b * 32; }
            else         { rows_x = false; cols_x = false;
                           pot  = (k & 1) ? py1  : py0;  potG  = (k & 1) ? pyG1 : pyG0;
                           outp = (k & 1) ? py0  : py1;  outpG = (k & 1) ? pyG0 : pyG1;
                           avg = true; rows_pb = 32; row0g = (b - 128) * 32; }
        } else {
            int k = h >> 1;         // xx iteration
            if (b < 128) { rows_x = true; cols_x = false; pot = g; potG = gG; outp = f; outpG = fG; rows_pb = 32; row0g = b * 32; }
            else         { rows_x = true; cols_x = true;
                           pot  = (k & 1) ? px1  : px0;  potG  = (k & 1) ? pxG1 : pxG0;
                           outp = (k & 1) ? px0  : px1;  outpG = (k & 1) ? pxG0 : pxG1;
                           avg = true; rows_pb = 32; row0g = (b - 128) * 32; }
        }

        // ---- restage G pair (pB[].zw): single 8B load of pre-scaled G ----
        float4* cpA = cols_x ? pAx : pAy;
        float4* cpB = cols_x ? pBx : pBy;
        const float* ccn = cols_x ? cnx : cny;
        for (int p = tid; p < 2048; p += NTHR) {
            float2 g2;
            if (isU) {
                float2 cn2 = ((const float2*)ccn)[p];
                g2 = make_float2(-cn2.x * S_U, -cn2.y * S_U);
            } else {
                g2 = gload2(potG + 2 * p);
            }
            ((float2*)&cpB[p])[1] = g2;
        }
        __syncthreads();

        // ---- wave tasks: 4 rows x 2048 cols each ----
        const float* rAf = (const float*)(rows_x ? pAx : pAy);
        const float* rBf = (const float*)(rows_x ? pBx : pBy);
        const int ntask = rows_pb >> 1;          // (rows_pb/4 groups) x 2 halves
        for (int t = wave; t < ntask; t += 16) {
            int grp = t >> 1, half = t & 1;
            int lr0 = grp << 2;
            int r0g = row0g + lr0;
            if (isU) run_task<true >(cpA, cpB, rAf, rBf, r0g, half, lane, scale, part2, lr0);
            else     run_task<false>(cpA, cpB, rAf, rBf, r0g, half, lane, scale, part2, lr0);
        }
        __syncthreads();

        // ---- finalize: merge 16 partials; write raw AND pre-scaled G ----
        const float* rcn = rows_x ? cnx : cny;
        if (tid < rows_pb) {
            float2 pv2[16];
#pragma unroll
            for (int q = 0; q < 16; ++q) pv2[q] = part2[tid * 16 + q];
            float mm = pv2[0].x;
#pragma unroll
            for (int q = 1; q < 15; q += 2) mm = max3f(mm, pv2[q].x, pv2[q + 1].x);
            mm = fmaxf(mm, pv2[15].x);
            float ss = 0.0f;
#pragma unroll
            for (int q = 0; q < 16; ++q) ss += pv2[q].y * fexp2(pv2[q].x - mm);
            int rg = row0g + tid;
            float rn = rcn[rg];
            float lse2 = mm + flog2(ss) - rn * scale;    // + X_i
            float val;
            if (isU) {
                val = lse2;
            } else {
                val = -E2 * (lse2 - 12.0f);               // log2(4096)=12
                if (avg) val = 0.5f * (gload(pot + rg) + val);
            }
            gstore(outp + rg, val);
            if (outpG) gstore(outpG + rg, (val - rn) * INV_E2);
        }

        group_barrier(cctr, crel, 128u * (unsigned)(h + 1), (unsigned)(h + 1), bb);
    }

    // ---- final reduction (block 0; must also wait for group B) ----
    if (b == 0) {
        if (tid == 0) {
            while (__hip_atomic_load(relB, __ATOMIC_RELAXED, __HIP_MEMORY_SCOPE_SYSTEM) < 41u)
                __builtin_amdgcn_s_sleep(1);
        }
        __syncthreads();

        float sf = 0.f, sg = 0.f, sx = 0.f, sy = 0.f, um = -1e30f, us = 0.f;
        for (int i = tid; i < NPT; i += NTHR) {
            sf += gload(ffin + i); sg += gload(g + i);
            sx += gload(fxv + i);  sy += gload(fyv + i);
            float v = gload(uls + i);
            float mn = fmaxf(um, v);
            us = us * fexp2(um - mn) + fexp2(v - mn);
            um = mn;
        }
#pragma unroll
        for (int off = 1; off < 64; off <<= 1) {
            sf += __shfl_xor(sf, off, 64);
            sg += __shfl_xor(sg, off, 64);
            sx += __shfl_xor(sx, off, 64);
            sy += __shfl_xor(sy, off, 64);
            float mo = __shfl_xor(um, off, 64);
            float so = __shfl_xor(us, off, 64);
            float mn = fmaxf(um, mo);
            us = us * fexp2(um - mn) + so * fexp2(mo - mn);
            um = mn;
        }
        __syncthreads();
        if (lane == 0) {
            float* red = smem;
            red[wave * 6 + 0] = sf; red[wave * 6 + 1] = sg; red[wave * 6 + 2] = sx;
            red[wave * 6 + 3] = sy; red[wave * 6 + 4] = um; red[wave * 6 + 5] = us;
        }
        __syncthreads();
        if (tid == 0) {
            float* red = smem;
            float Sf = 0, Sg = 0, Sx = 0, Sy = 0, Um = -1e30f, Us = 0;
            for (int w = 0; w < 16; ++w) {
                Sf += red[w * 6 + 0]; Sg += red[w * 6 + 1];
                Sx += red[w * 6 + 2]; Sy += red[w * 6 + 3];
                float mo = red[w * 6 + 4], so = red[w * 6 + 5];
                float mn = fmaxf(Um, mo);
                Us = Us * fexp2(Um - mn) + so * fexp2(mo - mn);
                Um = mn;
            }
            float mean = (Sf + Sg - Sx - Sy) * (1.0f / 4096.0f);
            float U = LN2F * (Um + flog2(Us)) - logf(4096.0f * 4095.0f);
            out[0] = mean + U;
        }
    }
}

extern "C" void kernel_launch(void* const* d_in, const int* in_sizes, int n_in,
                              void* d_out, int out_size, void* d_ws, size_t ws_size,
                              hipStream_t stream) {
    const float* x = (const float*)d_in[0];
    const float* y = (const float*)d_in[1];
    float* ws  = (float*)d_ws;
    float* out = (float*)d_out;

    (void)hipFuncSetAttribute((const void*)sink_main,
                              hipFuncAttributeMaxDynamicSharedMemorySize, SMEM_BYTES);

    sink_init<<<4, 1024, 0, stream>>>(x, y, ws);
    sink_main<<<NBLK, NTHR, SMEM_BYTES, stream>>>(x, y, ws, out);
}